// Round 1
// baseline (2539.317 us; speedup 1.0000x reference)
//
#include <hip/hip_runtime.h>
#include <hip/hip_bf16.h>

#define B_ 2
#define S_ 2048
#define D_ 4096
#define H_ 32
#define KVH_ 8
#define HD_ 128
#define SCALE_ 0.08838834764831845f
#define NEG_ (-1000000000.0f)

typedef unsigned short u16;
typedef __attribute__((ext_vector_type(8))) __bf16 bf16x8;
typedef __attribute__((ext_vector_type(4))) float f32x4;

__device__ __forceinline__ f32x4 mfma16(bf16x8 a, bf16x8 b, f32x4 c) {
    return __builtin_amdgcn_mfma_f32_16x16x32_bf16(a, b, c, 0, 0, 0);
}

__device__ __forceinline__ u16 f2bf(float f) {
    union { float f; unsigned u; } v; v.f = f;
    unsigned r = v.u + 0x7FFFu + ((v.u >> 16) & 1u);
    return (u16)(r >> 16);
}

// ---------------- fp32 -> bf16 convert ----------------
__global__ __launch_bounds__(256) void cvt_bf16_k(const float* __restrict__ in,
                                                  u16* __restrict__ out, int n) {
    int stride = gridDim.x * blockDim.x * 4;
    for (int i = (blockIdx.x * blockDim.x + threadIdx.x) * 4; i < n; i += stride) {
        f32x4 v = *reinterpret_cast<const f32x4*>(in + i);
        ushort4 o;
        o.x = f2bf(v[0]); o.y = f2bf(v[1]); o.z = f2bf(v[2]); o.w = f2bf(v[3]);
        *reinterpret_cast<ushort4*>(out + i) = o;
    }
}

// ---------------- zero the strictly-upper causal tiles of p ----------------
__global__ __launch_bounds__(256) void zero_upper_k(float* __restrict__ p) {
    int idx  = blockIdx.x;            // B*H*S rows
    int bh   = idx >> 11;
    int srow = idx & (S_ - 1);
    int start = ((srow >> 7) + 1) * 128;   // attn kernel writes cols [0, start)
    float* rowp = p + ((size_t)bh * S_ + srow) * S_;
    f32x4 z = 0.f;
    for (int c = start + threadIdx.x * 4; c < S_; c += 1024)
        *reinterpret_cast<f32x4*>(rowp + c) = z;
}

// ---------------- QKV projection GEMM + bias + RoPE ----------------
// C[m][n] = sum_k X[m][k] * W[n][k].  Tile 128x128, 4 waves of 32x128, BK=32.
// grid.x: 0..31 Q col-tiles (head = bx), 32..39 K, 40..47 V. grid.y: M/128.
__global__ __launch_bounds__(256) void gemm_qkv_k(
    const u16* __restrict__ Xb, const u16* __restrict__ Wq,
    const u16* __restrict__ Wk, const u16* __restrict__ Wv,
    const float* __restrict__ bq, const float* __restrict__ bk,
    const float* __restrict__ bv,
    const float* __restrict__ cosb, const float* __restrict__ sinb,
    u16* __restrict__ Qb, u16* __restrict__ Kb, u16* __restrict__ Vb) {
    __shared__ __align__(16) unsigned char As[128 * 80];  // [128][40] bf16, pad 40 => conflict-free frag reads
    __shared__ __align__(16) unsigned char Bs[128 * 80];

    const int tid = threadIdx.x, w = tid >> 6, l = tid & 63;
    const int l15 = l & 15, l4 = l >> 4;
    const int bx = blockIdx.x, m0 = blockIdx.y * 128;

    const u16* Wp; const float* bias; int nl0, mode;
    if (bx < 32)      { Wp = Wq; bias = bq; nl0 = bx * 128;        mode = 0; }
    else if (bx < 40) { Wp = Wk; bias = bk; nl0 = (bx - 32) * 128; mode = 1; }
    else              { Wp = Wv; bias = bv; nl0 = (bx - 40) * 128; mode = 2; }

    f32x4 acc[2][8];
#pragma unroll
    for (int i = 0; i < 2; i++)
#pragma unroll
        for (int j = 0; j < 8; j++) acc[i][j] = 0.f;

    const int c0 = tid, c1 = tid + 256;
    const int r0 = c0 >> 2, kk0 = (c0 & 3) * 8;
    const int r1 = c1 >> 2, kk1 = (c1 & 3) * 8;

    for (int kt = 0; kt < 128; kt++) {
        const int kbase = kt * 32;
        __syncthreads();
        *reinterpret_cast<uint4*>(As + r0 * 80 + kk0 * 2) =
            *reinterpret_cast<const uint4*>(Xb + (size_t)(m0 + r0) * D_ + kbase + kk0);
        *reinterpret_cast<uint4*>(As + r1 * 80 + kk1 * 2) =
            *reinterpret_cast<const uint4*>(Xb + (size_t)(m0 + r1) * D_ + kbase + kk1);
        *reinterpret_cast<uint4*>(Bs + r0 * 80 + kk0 * 2) =
            *reinterpret_cast<const uint4*>(Wp + (size_t)(nl0 + r0) * D_ + kbase + kk0);
        *reinterpret_cast<uint4*>(Bs + r1 * 80 + kk1 * 2) =
            *reinterpret_cast<const uint4*>(Wp + (size_t)(nl0 + r1) * D_ + kbase + kk1);
        __syncthreads();
        bf16x8 af[2], bf[8];
        af[0] = *reinterpret_cast<const bf16x8*>(As + (w * 32 + l15) * 80 + l4 * 16);
        af[1] = *reinterpret_cast<const bf16x8*>(As + (w * 32 + 16 + l15) * 80 + l4 * 16);
#pragma unroll
        for (int nf = 0; nf < 8; nf++)
            bf[nf] = *reinterpret_cast<const bf16x8*>(Bs + (nf * 16 + l15) * 80 + l4 * 16);
#pragma unroll
        for (int rf = 0; rf < 2; rf++)
#pragma unroll
            for (int nf = 0; nf < 8; nf++)
                acc[rf][nf] = mfma16(af[rf], bf[nf], acc[rf][nf]);
    }

    const int head = nl0 >> 7;
#pragma unroll
    for (int rf = 0; rf < 2; rf++) {
#pragma unroll
        for (int reg = 0; reg < 4; reg++) {
            const int mg = m0 + w * 32 + rf * 16 + l4 * 4 + reg;
            const int b = mg >> 11, s = mg & (S_ - 1);
            float v[8];
#pragma unroll
            for (int nf = 0; nf < 8; nf++)
                v[nf] = acc[rf][nf][reg] + bias[nl0 + nf * 16 + l15];
            u16* dst;
            if (mode == 0)      dst = Qb + (((size_t)b * H_   + head) * S_ + s) * HD_;
            else if (mode == 1) dst = Kb + (((size_t)b * KVH_ + head) * S_ + s) * HD_;
            else                dst = Vb + (((size_t)b * KVH_ + head) * S_ + s) * HD_;
            if (mode < 2) {
                const float* cp = cosb + ((size_t)b * S_ + s) * HD_;
                const float* sp = sinb + ((size_t)b * S_ + s) * HD_;
                float o[8];
#pragma unroll
                for (int nf = 0; nf < 4; nf++) {
                    const int dlo = nf * 16 + l15;
                    float cl = cp[dlo], sl = sp[dlo];
                    float ch = cp[dlo + 64], sh = sp[dlo + 64];
                    o[nf]     = v[nf] * cl - v[nf + 4] * sl;       // d < 64: x*c - x_hi*s
                    o[nf + 4] = v[nf + 4] * ch + v[nf] * sh;       // d >=64: x*c + x_lo*s
                }
#pragma unroll
                for (int nf = 0; nf < 8; nf++) dst[nf * 16 + l15] = f2bf(o[nf]);
            } else {
#pragma unroll
                for (int nf = 0; nf < 8; nf++) dst[nf * 16 + l15] = f2bf(v[nf]);
            }
        }
    }
}

// ---------------- output projection GEMM ----------------
__global__ __launch_bounds__(256) void gemm_out_k(
    const u16* __restrict__ Ctx, const u16* __restrict__ Wo,
    const float* __restrict__ bo, float* __restrict__ outp) {
    __shared__ __align__(16) unsigned char As[128 * 80];
    __shared__ __align__(16) unsigned char Bs[128 * 80];

    const int tid = threadIdx.x, w = tid >> 6, l = tid & 63;
    const int l15 = l & 15, l4 = l >> 4;
    const int n0 = blockIdx.x * 128, m0 = blockIdx.y * 128;

    f32x4 acc[2][8];
#pragma unroll
    for (int i = 0; i < 2; i++)
#pragma unroll
        for (int j = 0; j < 8; j++) acc[i][j] = 0.f;

    const int c0 = tid, c1 = tid + 256;
    const int r0 = c0 >> 2, kk0 = (c0 & 3) * 8;
    const int r1 = c1 >> 2, kk1 = (c1 & 3) * 8;

    for (int kt = 0; kt < 128; kt++) {
        const int kbase = kt * 32;
        __syncthreads();
        *reinterpret_cast<uint4*>(As + r0 * 80 + kk0 * 2) =
            *reinterpret_cast<const uint4*>(Ctx + (size_t)(m0 + r0) * D_ + kbase + kk0);
        *reinterpret_cast<uint4*>(As + r1 * 80 + kk1 * 2) =
            *reinterpret_cast<const uint4*>(Ctx + (size_t)(m0 + r1) * D_ + kbase + kk1);
        *reinterpret_cast<uint4*>(Bs + r0 * 80 + kk0 * 2) =
            *reinterpret_cast<const uint4*>(Wo + (size_t)(n0 + r0) * D_ + kbase + kk0);
        *reinterpret_cast<uint4*>(Bs + r1 * 80 + kk1 * 2) =
            *reinterpret_cast<const uint4*>(Wo + (size_t)(n0 + r1) * D_ + kbase + kk1);
        __syncthreads();
        bf16x8 af[2], bf[8];
        af[0] = *reinterpret_cast<const bf16x8*>(As + (w * 32 + l15) * 80 + l4 * 16);
        af[1] = *reinterpret_cast<const bf16x8*>(As + (w * 32 + 16 + l15) * 80 + l4 * 16);
#pragma unroll
        for (int nf = 0; nf < 8; nf++)
            bf[nf] = *reinterpret_cast<const bf16x8*>(Bs + (nf * 16 + l15) * 80 + l4 * 16);
#pragma unroll
        for (int rf = 0; rf < 2; rf++)
#pragma unroll
            for (int nf = 0; nf < 8; nf++)
                acc[rf][nf] = mfma16(af[rf], bf[nf], acc[rf][nf]);
    }

#pragma unroll
    for (int rf = 0; rf < 2; rf++)
#pragma unroll
        for (int reg = 0; reg < 4; reg++) {
            const int mg = m0 + w * 32 + rf * 16 + l4 * 4 + reg;
#pragma unroll
            for (int nf = 0; nf < 8; nf++) {
                const int cg = n0 + nf * 16 + l15;
                outp[(size_t)mg * D_ + cg] = acc[rf][nf][reg] + bo[cg];
            }
        }
}

// ---------------- fused causal attention, 2-pass online softmax ----------------
// block = 256 thr (4 waves), each block owns (b, h, 128 q-rows).
// LDS: [0,32KB) K-tile (XOR-swizzled) aliased later by P-tile; [32KB,64KB) V^T tile.
__global__ __launch_bounds__(256) void attn_k(
    const u16* __restrict__ Qb, const u16* __restrict__ Kb, const u16* __restrict__ Vb,
    float* __restrict__ pout, u16* __restrict__ Ctx) {
    __shared__ __align__(16) unsigned char smem[65536];
    const int qt = blockIdx.x, h = blockIdx.y, b = blockIdx.z;
    const int kvh = h >> 2;
    const int tid = threadIdx.x, w = tid >> 6, l = tid & 63;
    const int l15 = l & 15, l4 = l >> 4;
    const u16* Qp = Qb + ((size_t)b * H_ + h) * S_ * HD_;
    const u16* Kp = Kb + ((size_t)b * KVH_ + kvh) * S_ * HD_;
    const u16* Vp = Vb + ((size_t)b * KVH_ + kvh) * S_ * HD_;
    const int qrow0 = qt * 128 + w * 32;

    // Q fragments in registers (A-operand: row = l&15, k = (l>>4)*8+j)
    bf16x8 qf[2][4];
#pragma unroll
    for (int rf = 0; rf < 2; rf++)
#pragma unroll
        for (int kf = 0; kf < 4; kf++)
            qf[rf][kf] = *reinterpret_cast<const bf16x8*>(
                Qp + (size_t)(qrow0 + rf * 16 + l15) * HD_ + kf * 32 + l4 * 8);

    float m_run[8], l_run[8];
#pragma unroll
    for (int i = 0; i < 8; i++) { m_run[i] = -3.0e38f; l_run[i] = 0.f; }

    // ---- pass 1: row max + sumexp ----
    for (int kt = 0; kt <= qt; kt++) {
        __syncthreads();
#pragma unroll
        for (int i = 0; i < 8; i++) {                       // stage K tile, swizzled
            int c = tid + i * 256;
            int kr = c >> 4, d0 = (c & 15) * 8;
            uint4 v = *reinterpret_cast<const uint4*>(Kp + (size_t)(kt * 128 + kr) * HD_ + d0);
            *reinterpret_cast<uint4*>(smem + kr * 256 + ((d0 * 2) ^ ((kr & 7) << 4))) = v;
        }
        __syncthreads();
        f32x4 sfr[2][8];
#pragma unroll
        for (int i = 0; i < 2; i++)
#pragma unroll
            for (int j = 0; j < 8; j++) sfr[i][j] = 0.f;
#pragma unroll
        for (int cf = 0; cf < 8; cf++) {
#pragma unroll
            for (int kf = 0; kf < 4; kf++) {
                const int row = cf * 16 + l15;
                bf16x8 bfr = *reinterpret_cast<const bf16x8*>(
                    smem + row * 256 + ((kf * 64 + l4 * 16) ^ ((row & 7) << 4)));
                sfr[0][cf] = mfma16(qf[0][kf], bfr, sfr[0][cf]);
                sfr[1][cf] = mfma16(qf[1][kf], bfr, sfr[1][cf]);
            }
        }
#pragma unroll
        for (int rf = 0; rf < 2; rf++) {
#pragma unroll
            for (int reg = 0; reg < 4; reg++) {
                const int i = rf * 4 + reg;
                const int srow = qrow0 + rf * 16 + l4 * 4 + reg;
                float vals[8], lmax = -3.0e38f;
#pragma unroll
                for (int cf = 0; cf < 8; cf++) {
                    int kg = kt * 128 + cf * 16 + l15;
                    vals[cf] = (sfr[rf][cf][reg] + ((kg <= srow) ? 0.f : NEG_)) * SCALE_;
                    lmax = fmaxf(lmax, vals[cf]);
                }
#pragma unroll
                for (int mk = 1; mk < 16; mk <<= 1) lmax = fmaxf(lmax, __shfl_xor(lmax, mk, 64));
                float newm = fmaxf(m_run[i], lmax);
                float psum = 0.f;
#pragma unroll
                for (int cf = 0; cf < 8; cf++) psum += __expf(vals[cf] - newm);
#pragma unroll
                for (int mk = 1; mk < 16; mk <<= 1) psum += __shfl_xor(psum, mk, 64);
                float sc = (m_run[i] < -1.0e37f) ? 0.f : __expf(m_run[i] - newm);
                l_run[i] = l_run[i] * sc + psum;
                m_run[i] = newm;
            }
        }
    }

    float inv_l[8];
#pragma unroll
    for (int i = 0; i < 8; i++) inv_l[i] = 1.f / l_run[i];

    f32x4 ctx[2][8];
#pragma unroll
    for (int i = 0; i < 2; i++)
#pragma unroll
        for (int j = 0; j < 8; j++) ctx[i][j] = 0.f;

    // ---- pass 2: recompute S, write p, accumulate PV ----
    for (int kt = 0; kt <= qt; kt++) {
        __syncthreads();
#pragma unroll
        for (int i = 0; i < 8; i++) {                       // stage K tile
            int c = tid + i * 256;
            int kr = c >> 4, d0 = (c & 15) * 8;
            uint4 v = *reinterpret_cast<const uint4*>(Kp + (size_t)(kt * 128 + kr) * HD_ + d0);
            *reinterpret_cast<uint4*>(smem + kr * 256 + ((d0 * 2) ^ ((kr & 7) << 4))) = v;
        }
#pragma unroll
        for (int i = 0; i < 8; i++) {                       // stage V transposed, swizzled
            int c = tid + i * 256;
            int kk = c >> 4, d0 = (c & 15) * 8;
            uint4 v = *reinterpret_cast<const uint4*>(Vp + (size_t)(kt * 128 + kk) * HD_ + d0);
            const u16* us = reinterpret_cast<const u16*>(&v);
#pragma unroll
            for (int j = 0; j < 8; j++) {
                int d = d0 + j;
                *reinterpret_cast<u16*>(smem + 32768 + d * 256 +
                                        ((kk * 2) ^ (((d & 7) ^ ((d >> 3) & 7)) << 4))) = us[j];
            }
        }
        __syncthreads();
        f32x4 sfr[2][8];
#pragma unroll
        for (int i = 0; i < 2; i++)
#pragma unroll
            for (int j = 0; j < 8; j++) sfr[i][j] = 0.f;
#pragma unroll
        for (int cf = 0; cf < 8; cf++) {
#pragma unroll
            for (int kf = 0; kf < 4; kf++) {
                const int row = cf * 16 + l15;
                bf16x8 bfr = *reinterpret_cast<const bf16x8*>(
                    smem + row * 256 + ((kf * 64 + l4 * 16) ^ ((row & 7) << 4)));
                sfr[0][cf] = mfma16(qf[0][kf], bfr, sfr[0][cf]);
                sfr[1][cf] = mfma16(qf[1][kf], bfr, sfr[1][cf]);
            }
        }
        __syncthreads();   // all waves done reading K tile; its LDS now becomes P tile
#pragma unroll
        for (int rf = 0; rf < 2; rf++) {
#pragma unroll
            for (int cf = 0; cf < 8; cf++) {
#pragma unroll
                for (int reg = 0; reg < 4; reg++) {
                    const int i = rf * 4 + reg;
                    const int rl = w * 32 + rf * 16 + l4 * 4 + reg;
                    const int srow = qt * 128 + rl;
                    const int kg = kt * 128 + cf * 16 + l15;
                    float logit = (sfr[rf][cf][reg] + ((kg <= srow) ? 0.f : NEG_)) * SCALE_;
                    float pv = __expf(logit - m_run[i]) * inv_l[i];
                    pout[((size_t)(b * H_ + h) * S_ + srow) * S_ + kg] = pv;
                    *reinterpret_cast<u16*>(smem + rl * 256 +
                                            (((cf * 16 + l15) * 2) ^ ((rl & 7) << 4))) = f2bf(pv);
                }
            }
        }
        __syncthreads();
#pragma unroll
        for (int kf = 0; kf < 4; kf++) {                    // PV MFMA
            bf16x8 paf[2];
#pragma unroll
            for (int rf = 0; rf < 2; rf++) {
                const int rl = w * 32 + rf * 16 + l15;
                paf[rf] = *reinterpret_cast<const bf16x8*>(
                    smem + rl * 256 + ((kf * 64 + l4 * 16) ^ ((rl & 7) << 4)));
            }
#pragma unroll
            for (int cf = 0; cf < 8; cf++) {
                const int d = cf * 16 + l15;
                bf16x8 bvf = *reinterpret_cast<const bf16x8*>(
                    smem + 32768 + d * 256 +
                    ((kf * 64 + l4 * 16) ^ (((d & 7) ^ ((d >> 3) & 7)) << 4)));
                ctx[0][cf] = mfma16(paf[0], bvf, ctx[0][cf]);
                ctx[1][cf] = mfma16(paf[1], bvf, ctx[1][cf]);
            }
        }
    }

#pragma unroll
    for (int rf = 0; rf < 2; rf++)
#pragma unroll
        for (int cf = 0; cf < 8; cf++)
#pragma unroll
            for (int reg = 0; reg < 4; reg++) {
                const int s = qt * 128 + w * 32 + rf * 16 + l4 * 4 + reg;
                const int d = cf * 16 + l15;
                Ctx[((size_t)b * S_ + s) * D_ + h * HD_ + d] = f2bf(ctx[rf][cf][reg]);
            }
}

extern "C" void kernel_launch(void* const* d_in, const int* in_sizes, int n_in,
                              void* d_out, int out_size, void* d_ws, size_t ws_size,
                              hipStream_t stream) {
    const float* hs   = (const float*)d_in[0];
    const float* cosb = (const float*)d_in[1];
    const float* sinb = (const float*)d_in[2];
    // d_in[3] attention_mask: deterministic causal; recomputed in-kernel.
    const float* wq = (const float*)d_in[4];
    const float* bq = (const float*)d_in[5];
    const float* wk = (const float*)d_in[6];
    const float* bk = (const float*)d_in[7];
    const float* wv = (const float*)d_in[8];
    const float* bv = (const float*)d_in[9];
    const float* wo = (const float*)d_in[10];
    const float* bo = (const float*)d_in[11];

    char* ws = (char*)d_ws;
    // 128 MB workspace layout (regions reused once their last reader is done):
    u16* Xb  = (u16*)(ws);                        // 33.5MB  hidden bf16, later Ctx
    u16* Wqb = (u16*)(ws + 33554432ull);          // 33.5MB  wq bf16, later wo bf16
    u16* Wkb = (u16*)(ws + 67108864ull);          // 8.4MB
    u16* Wvb = (u16*)(ws + 75497472ull);          // 8.4MB
    u16* Qb  = (u16*)(ws + 83886080ull);          // 33.5MB  [B,H,S,HD]
    u16* Kb  = (u16*)(ws + 117440512ull);         // 8.4MB   [B,KVH,S,HD]
    u16* Vb  = (u16*)(ws + 125829120ull);         // 8.4MB

    float* outp = (float*)d_out;                  // (B,S,D) = 16,777,216 floats
    float* pout = outp + 16777216ull;             // (B,H,S,S) = 268,435,456 floats

    cvt_bf16_k<<<2048, 256, 0, stream>>>(hs, Xb, 16777216);
    cvt_bf16_k<<<2048, 256, 0, stream>>>(wq, Wqb, 16777216);
    cvt_bf16_k<<<512, 256, 0, stream>>>(wk, Wkb, 4194304);
    cvt_bf16_k<<<512, 256, 0, stream>>>(wv, Wvb, 4194304);

    gemm_qkv_k<<<dim3(48, 32), 256, 0, stream>>>(Xb, Wqb, Wkb, Wvb, bq, bk, bv,
                                                 cosb, sinb, Qb, Kb, Vb);

    cvt_bf16_k<<<2048, 256, 0, stream>>>(wo, Wqb, 16777216);   // Wqb slot now holds wo
    zero_upper_k<<<B_ * H_ * S_, 256, 0, stream>>>(pout);

    attn_k<<<dim3(16, 32, 2), 256, 0, stream>>>(Qb, Kb, Vb, pout, Xb /*Ctx*/);

    gemm_out_k<<<dim3(32, 32), 256, 0, stream>>>(Xb /*Ctx*/, Wqb /*Wo*/, bo, outp);
}

// Round 2
// 2002.310 us; speedup vs baseline: 1.2682x; 1.2682x over previous
//
#include <hip/hip_runtime.h>
#include <hip/hip_bf16.h>

#define B_ 2
#define S_ 2048
#define D_ 4096
#define H_ 32
#define KVH_ 8
#define HD_ 128
#define SCALE_ 0.08838834764831845f
#define NEG_ (-1000000000.0f)

typedef unsigned short u16;
typedef __attribute__((ext_vector_type(8))) __bf16 bf16x8;
typedef __attribute__((ext_vector_type(4))) float f32x4;

__device__ __forceinline__ f32x4 mfma16(bf16x8 a, bf16x8 b, f32x4 c) {
    return __builtin_amdgcn_mfma_f32_16x16x32_bf16(a, b, c, 0, 0, 0);
}

__device__ __forceinline__ u16 f2bf(float f) {
    union { float f; unsigned u; } v; v.f = f;
    unsigned r = v.u + 0x7FFFu + ((v.u >> 16) & 1u);
    return (u16)(r >> 16);
}

// async global->LDS, 16B per lane. LDS dest is wave-uniform base + lane*16;
// swizzling is done by pre-swizzling the per-lane GLOBAL source address.
__device__ __forceinline__ void gld16(const void* g, void* l) {
    __builtin_amdgcn_global_load_lds(
        (const __attribute__((address_space(1))) void*)g,
        (__attribute__((address_space(3))) void*)l, 16, 0, 0);
}

// ---------------- fp32 -> bf16 convert ----------------
__global__ __launch_bounds__(256) void cvt_bf16_k(const float* __restrict__ in,
                                                  u16* __restrict__ out, int n) {
    int stride = gridDim.x * blockDim.x * 4;
    for (int i = (blockIdx.x * blockDim.x + threadIdx.x) * 4; i < n; i += stride) {
        f32x4 v = *reinterpret_cast<const f32x4*>(in + i);
        ushort4 o;
        o.x = f2bf(v[0]); o.y = f2bf(v[1]); o.z = f2bf(v[2]); o.w = f2bf(v[3]);
        *reinterpret_cast<ushort4*>(out + i) = o;
    }
}

// ---------------- QKV projection GEMM + bias + RoPE (m97-style K loop) ------
// C[m][n] = sum_k X[m][k] * W[n][k]. 128x128 tile, BK=64, global_load_lds
// staging (linear LDS + inverse-swizzled source), XOR-swizzled ds_read_b128.
// grid.x: 0..31 Q (head=bx), 32..39 K, 40..47 V(-> transposed out). grid.y M/128.
__global__ __launch_bounds__(256) void gemm_qkv_k(
    const u16* __restrict__ Xb, const u16* __restrict__ Wq,
    const u16* __restrict__ Wk, const u16* __restrict__ Wv,
    const float* __restrict__ bq, const float* __restrict__ bk,
    const float* __restrict__ bv,
    const float* __restrict__ cosb, const float* __restrict__ sinb,
    u16* __restrict__ Qb, u16* __restrict__ Kb, u16* __restrict__ VTb) {
    __shared__ __align__(16) unsigned char As[16384];   // [128][64] bf16 linear
    __shared__ __align__(16) unsigned char Bs[16384];

    const int tid = threadIdx.x, w = tid >> 6, l = tid & 63;
    const int l15 = l & 15, l4 = l >> 4;
    const int bx = blockIdx.x, m0 = blockIdx.y * 128;

    const u16* Wp; const float* bias; int nl0, mode;
    if (bx < 32)      { Wp = Wq; bias = bq; nl0 = bx * 128;        mode = 0; }
    else if (bx < 40) { Wp = Wk; bias = bk; nl0 = (bx - 32) * 128; mode = 1; }
    else              { Wp = Wv; bias = bv; nl0 = (bx - 40) * 128; mode = 2; }

    f32x4 acc[2][8];
#pragma unroll
    for (int i = 0; i < 2; i++)
#pragma unroll
        for (int j = 0; j < 8; j++) acc[i][j] = 0.f;

    // staging: chunk ch covers 8 rows of 128B; lane l -> row ch*8+(l>>3), col (l&7)*16
    const int srow8 = l >> 3;
    const int scol  = ((l & 7) * 16) ^ (srow8 << 4);    // inverse-swizzled src col
    const int fr_swz = (l15 & 7) << 4;                  // frag-read swizzle

    for (int kt = 0; kt < 64; kt++) {
        const size_t kb2 = (size_t)kt * 128;            // byte col offset
        __syncthreads();
#pragma unroll
        for (int j = 0; j < 4; j++) {
            const int ch = w * 4 + j;
            const int r = ch * 8 + srow8;
            gld16((const char*)Xb + ((size_t)(m0 + r) * D_) * 2 + kb2 + scol,
                  (char*)As + ch * 1024 + l * 16);
            gld16((const char*)Wp + ((size_t)(nl0 + r) * D_) * 2 + kb2 + scol,
                  (char*)Bs + ch * 1024 + l * 16);
        }
        __syncthreads();
#pragma unroll
        for (int kf = 0; kf < 2; kf++) {
            const int co = (kf * 64 + l4 * 16) ^ fr_swz;
            bf16x8 af0 = *reinterpret_cast<const bf16x8*>(As + (w * 32 + l15) * 128 + co);
            bf16x8 af1 = *reinterpret_cast<const bf16x8*>(As + (w * 32 + 16 + l15) * 128 + co);
            bf16x8 bf[8];
#pragma unroll
            for (int nf = 0; nf < 8; nf++)
                bf[nf] = *reinterpret_cast<const bf16x8*>(Bs + (nf * 16 + l15) * 128 + co);
#pragma unroll
            for (int nf = 0; nf < 8; nf++) {
                acc[0][nf] = mfma16(af0, bf[nf], acc[0][nf]);
                acc[1][nf] = mfma16(af1, bf[nf], acc[1][nf]);
            }
        }
    }

    const int head = nl0 >> 7;
#pragma unroll
    for (int rf = 0; rf < 2; rf++) {
#pragma unroll
        for (int reg = 0; reg < 4; reg++) {
            const int mg = m0 + w * 32 + rf * 16 + l4 * 4 + reg;
            const int b = mg >> 11, s = mg & (S_ - 1);
            float v[8];
#pragma unroll
            for (int nf = 0; nf < 8; nf++)
                v[nf] = acc[rf][nf][reg] + bias[nl0 + nf * 16 + l15];
            if (mode < 2) {
                const float* cp = cosb + ((size_t)b * S_ + s) * HD_;
                const float* sp = sinb + ((size_t)b * S_ + s) * HD_;
                float o[8];
#pragma unroll
                for (int nf = 0; nf < 4; nf++) {
                    const int dlo = nf * 16 + l15;
                    float cl = cp[dlo], sl = sp[dlo];
                    float ch = cp[dlo + 64], sh = sp[dlo + 64];
                    o[nf]     = v[nf] * cl - v[nf + 4] * sl;
                    o[nf + 4] = v[nf + 4] * ch + v[nf] * sh;
                }
                u16* dst = (mode == 0)
                    ? Qb + (((size_t)b * H_   + head) * S_ + s) * HD_
                    : Kb + (((size_t)b * KVH_ + head) * S_ + s) * HD_;
#pragma unroll
                for (int nf = 0; nf < 8; nf++) dst[nf * 16 + l15] = f2bf(o[nf]);
            } else {
                // V stored TRANSPOSED: [B][KVH][HD][S]
                u16* dstT = VTb + ((size_t)b * KVH_ + head) * HD_ * S_;
#pragma unroll
                for (int nf = 0; nf < 8; nf++)
                    dstT[(size_t)(nf * 16 + l15) * S_ + s] = f2bf(v[nf]);
            }
        }
    }
}

// ---------------- output projection GEMM (same m97 core) ----------------
__global__ __launch_bounds__(256) void gemm_out_k(
    const u16* __restrict__ Ctx, const u16* __restrict__ Wo,
    const float* __restrict__ bo, float* __restrict__ outp) {
    __shared__ __align__(16) unsigned char As[16384];
    __shared__ __align__(16) unsigned char Bs[16384];

    const int tid = threadIdx.x, w = tid >> 6, l = tid & 63;
    const int l15 = l & 15, l4 = l >> 4;
    const int n0 = blockIdx.x * 128, m0 = blockIdx.y * 128;

    f32x4 acc[2][8];
#pragma unroll
    for (int i = 0; i < 2; i++)
#pragma unroll
        for (int j = 0; j < 8; j++) acc[i][j] = 0.f;

    const int srow8 = l >> 3;
    const int scol  = ((l & 7) * 16) ^ (srow8 << 4);
    const int fr_swz = (l15 & 7) << 4;

    for (int kt = 0; kt < 64; kt++) {
        const size_t kb2 = (size_t)kt * 128;
        __syncthreads();
#pragma unroll
        for (int j = 0; j < 4; j++) {
            const int ch = w * 4 + j;
            const int r = ch * 8 + srow8;
            gld16((const char*)Ctx + ((size_t)(m0 + r) * D_) * 2 + kb2 + scol,
                  (char*)As + ch * 1024 + l * 16);
            gld16((const char*)Wo + ((size_t)(n0 + r) * D_) * 2 + kb2 + scol,
                  (char*)Bs + ch * 1024 + l * 16);
        }
        __syncthreads();
#pragma unroll
        for (int kf = 0; kf < 2; kf++) {
            const int co = (kf * 64 + l4 * 16) ^ fr_swz;
            bf16x8 af0 = *reinterpret_cast<const bf16x8*>(As + (w * 32 + l15) * 128 + co);
            bf16x8 af1 = *reinterpret_cast<const bf16x8*>(As + (w * 32 + 16 + l15) * 128 + co);
            bf16x8 bf[8];
#pragma unroll
            for (int nf = 0; nf < 8; nf++)
                bf[nf] = *reinterpret_cast<const bf16x8*>(Bs + (nf * 16 + l15) * 128 + co);
#pragma unroll
            for (int nf = 0; nf < 8; nf++) {
                acc[0][nf] = mfma16(af0, bf[nf], acc[0][nf]);
                acc[1][nf] = mfma16(af1, bf[nf], acc[1][nf]);
            }
        }
    }

#pragma unroll
    for (int rf = 0; rf < 2; rf++)
#pragma unroll
        for (int reg = 0; reg < 4; reg++) {
            const int mg = m0 + w * 32 + rf * 16 + l4 * 4 + reg;
#pragma unroll
            for (int nf = 0; nf < 8; nf++) {
                const int cg = n0 + nf * 16 + l15;
                outp[(size_t)mg * D_ + cg] = acc[rf][nf][reg] + bo[cg];
            }
        }
}

// ---------------- fused causal attention, balanced pairs ----------------
// grid (8,32,2): block pi handles q-tiles {15-pi, pi} -> uniform 17 k-tiles.
// 512 blocks = exactly 2/CU resident (64KB LDS). Also zero-fills p's upper
// triangle (anti-correlated with attn work -> stays uniform).
// LDS: [0,32KB) K tile (aliased by P tile); [32KB,64KB) V^T tile.
__global__ __launch_bounds__(256) void attn_k(
    const u16* __restrict__ Qb, const u16* __restrict__ Kb,
    const u16* __restrict__ VTb, float* __restrict__ pout, u16* __restrict__ Ctx) {
    __shared__ __align__(16) unsigned char smem[65536];
    const int pi = blockIdx.x, h = blockIdx.y, b = blockIdx.z;
    const int kvh = h >> 2;
    const int tid = threadIdx.x, w = tid >> 6, l = tid & 63;
    const int l15 = l & 15, l4 = l >> 4;
    const int fr_swz = (l15 & 7) << 4;
    const u16* Qp  = Qb  + ((size_t)b * H_ + h) * S_ * HD_;
    const u16* Kp  = Kb  + ((size_t)b * KVH_ + kvh) * S_ * HD_;
    const u16* VTp = VTb + ((size_t)b * KVH_ + kvh) * HD_ * S_;
    float* prow_base = pout + (size_t)(b * H_ + h) * S_ * S_;

    // staging: chunk ch covers 4 rows of 256B; lane l -> row ch*4+(l>>4), col (l&15)*16
    const int st_r4 = l >> 4;
    const int st_c  = (l & 15) * 16;

    for (int t = 0; t < 2; t++) {
        const int qt = t ? pi : 15 - pi;
        // ---- zero-fill p cols >= (qt+1)*128 for these 128 rows ----
        {
            const int start = (qt + 1) * 128;
            f32x4 zz = 0.f;
            for (int r = 0; r < 128; r++) {
                float* rowp = prow_base + (size_t)(qt * 128 + r) * S_;
                for (int c = start + tid * 4; c < S_; c += 1024)
                    *reinterpret_cast<f32x4*>(rowp + c) = zz;
            }
        }
        const int qrow0 = qt * 128 + w * 32;

        bf16x8 qf[2][4];
#pragma unroll
        for (int rf = 0; rf < 2; rf++)
#pragma unroll
            for (int kf = 0; kf < 4; kf++)
                qf[rf][kf] = *reinterpret_cast<const bf16x8*>(
                    Qp + (size_t)(qrow0 + rf * 16 + l15) * HD_ + kf * 32 + l4 * 8);

        float m_run[8], l_run[8];
#pragma unroll
        for (int i = 0; i < 8; i++) { m_run[i] = -3.0e38f; l_run[i] = 0.f; }

        // ---- pass 1: row max + sumexp ----
        for (int kt = 0; kt <= qt; kt++) {
            __syncthreads();
#pragma unroll
            for (int j = 0; j < 8; j++) {
                const int ch = w * 8 + j;
                const int r = ch * 4 + st_r4;
                gld16((const char*)Kp + (size_t)(kt * 128 + r) * 256 + (st_c ^ ((r & 7) << 4)),
                      (char*)smem + ch * 1024 + l * 16);
            }
            __syncthreads();
            f32x4 sfr[2][8];
#pragma unroll
            for (int i = 0; i < 2; i++)
#pragma unroll
                for (int j = 0; j < 8; j++) sfr[i][j] = 0.f;
#pragma unroll
            for (int cf = 0; cf < 8; cf++)
#pragma unroll
                for (int kf = 0; kf < 4; kf++) {
                    const int co = (kf * 64 + l4 * 16) ^ fr_swz;
                    bf16x8 bfr = *reinterpret_cast<const bf16x8*>(
                        smem + (cf * 16 + l15) * 256 + co);
                    sfr[0][cf] = mfma16(qf[0][kf], bfr, sfr[0][cf]);
                    sfr[1][cf] = mfma16(qf[1][kf], bfr, sfr[1][cf]);
                }
#pragma unroll
            for (int rf = 0; rf < 2; rf++) {
#pragma unroll
                for (int reg = 0; reg < 4; reg++) {
                    const int i = rf * 4 + reg;
                    const int srow = qrow0 + rf * 16 + l4 * 4 + reg;
                    float vals[8], lmax = -3.0e38f;
#pragma unroll
                    for (int cf = 0; cf < 8; cf++) {
                        int kg = kt * 128 + cf * 16 + l15;
                        vals[cf] = (sfr[rf][cf][reg] + ((kg <= srow) ? 0.f : NEG_)) * SCALE_;
                        lmax = fmaxf(lmax, vals[cf]);
                    }
#pragma unroll
                    for (int mk = 1; mk < 16; mk <<= 1)
                        lmax = fmaxf(lmax, __shfl_xor(lmax, mk, 64));
                    float newm = fmaxf(m_run[i], lmax);
                    float psum = 0.f;
#pragma unroll
                    for (int cf = 0; cf < 8; cf++) psum += __expf(vals[cf] - newm);
#pragma unroll
                    for (int mk = 1; mk < 16; mk <<= 1)
                        psum += __shfl_xor(psum, mk, 64);
                    float sc = (m_run[i] < -1.0e37f) ? 0.f : __expf(m_run[i] - newm);
                    l_run[i] = l_run[i] * sc + psum;
                    m_run[i] = newm;
                }
            }
        }

        float inv_l[8];
#pragma unroll
        for (int i = 0; i < 8; i++) inv_l[i] = 1.f / l_run[i];

        f32x4 ctx[2][8];
#pragma unroll
        for (int i = 0; i < 2; i++)
#pragma unroll
            for (int j = 0; j < 8; j++) ctx[i][j] = 0.f;

        // ---- pass 2: recompute S, write p, accumulate PV ----
        for (int kt = 0; kt <= qt; kt++) {
            __syncthreads();
#pragma unroll
            for (int j = 0; j < 8; j++) {
                const int ch = w * 8 + j;
                const int r = ch * 4 + st_r4;
                const int sc = st_c ^ ((r & 7) << 4);
                gld16((const char*)Kp + (size_t)(kt * 128 + r) * 256 + sc,
                      (char*)smem + ch * 1024 + l * 16);
                gld16((const char*)VTp + ((size_t)r * S_ + kt * 128) * 2 + sc,
                      (char*)smem + 32768 + ch * 1024 + l * 16);
            }
            __syncthreads();
            f32x4 sfr[2][8];
#pragma unroll
            for (int i = 0; i < 2; i++)
#pragma unroll
                for (int j = 0; j < 8; j++) sfr[i][j] = 0.f;
#pragma unroll
            for (int cf = 0; cf < 8; cf++)
#pragma unroll
                for (int kf = 0; kf < 4; kf++) {
                    const int co = (kf * 64 + l4 * 16) ^ fr_swz;
                    bf16x8 bfr = *reinterpret_cast<const bf16x8*>(
                        smem + (cf * 16 + l15) * 256 + co);
                    sfr[0][cf] = mfma16(qf[0][kf], bfr, sfr[0][cf]);
                    sfr[1][cf] = mfma16(qf[1][kf], bfr, sfr[1][cf]);
                }
            __syncthreads();   // K reads done; K region becomes P tile
#pragma unroll
            for (int rf = 0; rf < 2; rf++) {
#pragma unroll
                for (int reg = 0; reg < 4; reg++) {
                    const int i = rf * 4 + reg;
                    const int rl = w * 32 + rf * 16 + l4 * 4 + reg;
                    const int srow = qt * 128 + rl;
                    float* rowp = prow_base + (size_t)srow * S_ + kt * 128;
                    const int pswz = (rl & 7) << 4;
#pragma unroll
                    for (int cf = 0; cf < 8; cf++) {
                        const int kl = cf * 16 + l15;
                        const int kg = kt * 128 + kl;
                        float logit = (sfr[rf][cf][reg] + ((kg <= srow) ? 0.f : NEG_)) * SCALE_;
                        float pv = __expf(logit - m_run[i]) * inv_l[i];
                        rowp[kl] = pv;
                        *reinterpret_cast<u16*>(smem + rl * 256 + ((kl * 2) ^ pswz)) = f2bf(pv);
                    }
                }
            }
            __syncthreads();
#pragma unroll
            for (int kf = 0; kf < 4; kf++) {
                const int co = (kf * 64 + l4 * 16) ^ fr_swz;
                bf16x8 pa0 = *reinterpret_cast<const bf16x8*>(
                    smem + (w * 32 + l15) * 256 + co);
                bf16x8 pa1 = *reinterpret_cast<const bf16x8*>(
                    smem + (w * 32 + 16 + l15) * 256 + co);
#pragma unroll
                for (int cf = 0; cf < 8; cf++) {
                    bf16x8 bvf = *reinterpret_cast<const bf16x8*>(
                        smem + 32768 + (cf * 16 + l15) * 256 + co);
                    ctx[0][cf] = mfma16(pa0, bvf, ctx[0][cf]);
                    ctx[1][cf] = mfma16(pa1, bvf, ctx[1][cf]);
                }
            }
        }

#pragma unroll
        for (int rf = 0; rf < 2; rf++)
#pragma unroll
            for (int cf = 0; cf < 8; cf++)
#pragma unroll
                for (int reg = 0; reg < 4; reg++) {
                    const int s = qt * 128 + w * 32 + rf * 16 + l4 * 4 + reg;
                    const int d = cf * 16 + l15;
                    Ctx[((size_t)b * S_ + s) * D_ + h * HD_ + d] = f2bf(ctx[rf][cf][reg]);
                }
    }
}

extern "C" void kernel_launch(void* const* d_in, const int* in_sizes, int n_in,
                              void* d_out, int out_size, void* d_ws, size_t ws_size,
                              hipStream_t stream) {
    const float* hs   = (const float*)d_in[0];
    const float* cosb = (const float*)d_in[1];
    const float* sinb = (const float*)d_in[2];
    // d_in[3] attention_mask: deterministic causal; recomputed in-kernel.
    const float* wq = (const float*)d_in[4];
    const float* bq = (const float*)d_in[5];
    const float* wk = (const float*)d_in[6];
    const float* bk = (const float*)d_in[7];
    const float* wv = (const float*)d_in[8];
    const float* bv = (const float*)d_in[9];
    const float* wo = (const float*)d_in[10];
    const float* bo = (const float*)d_in[11];

    char* ws = (char*)d_ws;
    u16* Xb  = (u16*)(ws);                        // hidden bf16, later Ctx
    u16* Wqb = (u16*)(ws + 33554432ull);          // wq bf16, later wo bf16
    u16* Wkb = (u16*)(ws + 67108864ull);
    u16* Wvb = (u16*)(ws + 75497472ull);
    u16* Qb  = (u16*)(ws + 83886080ull);          // [B,H,S,HD]
    u16* Kb  = (u16*)(ws + 117440512ull);         // [B,KVH,S,HD]
    u16* VTb = (u16*)(ws + 125829120ull);         // [B,KVH,HD,S]  (transposed!)

    float* outp = (float*)d_out;
    float* pout = outp + 16777216ull;

    cvt_bf16_k<<<2048, 256, 0, stream>>>(hs, Xb, 16777216);
    cvt_bf16_k<<<2048, 256, 0, stream>>>(wq, Wqb, 16777216);
    cvt_bf16_k<<<512, 256, 0, stream>>>(wk, Wkb, 4194304);
    cvt_bf16_k<<<512, 256, 0, stream>>>(wv, Wvb, 4194304);

    gemm_qkv_k<<<dim3(48, 32), 256, 0, stream>>>(Xb, Wqb, Wkb, Wvb, bq, bk, bv,
                                                 cosb, sinb, Qb, Kb, VTb);

    cvt_bf16_k<<<2048, 256, 0, stream>>>(wo, Wqb, 16777216);   // Wqb slot -> wo

    attn_k<<<dim3(8, 32, 2), 256, 0, stream>>>(Qb, Kb, VTb, pout, Xb /*Ctx*/);

    gemm_out_k<<<dim3(32, 32), 256, 0, stream>>>(Xb /*Ctx*/, Wqb /*Wo*/, bo, outp);
}